// Round 6
// baseline (265.714 us; speedup 1.0000x reference)
//
#include <hip/hip_runtime.h>
#include <hip/hip_fp16.h>

#define Bsz 1024
#define Mm  2048
#define Rr  8192
#define EMAX 32   // ushort slots per E column (Poisson mean 4.1)
#define SMAX 64   // ushort slots per S row    (Poisson mean 16.4)

typedef unsigned short ushort_t;

// ---- pass 1: logcT[m][b] = log(conc[b][m]); zero ecnt + elist ----
// grid MUST be 512 blocks x 256 thr: 131072 threads == Rr*EMAX ushorts / 2
__global__ __launch_bounds__(256) void transpose_log(
    const float* __restrict__ conc, float* __restrict__ logcT,
    int* __restrict__ ecnt, unsigned int* __restrict__ elist32)
{
    const int g = blockIdx.x * 256 + threadIdx.x;
    if (g < Rr) ecnt[g] = 0;
    elist32[g] = 0;                       // zero all elist ushorts (weight e=0)

    __shared__ float tile[64][65];
    const int mt = (blockIdx.x % (Mm / 64)) * 64;
    const int bt = (blockIdx.x / (Mm / 64)) * 64;
    const int lm = threadIdx.x & 63;
    const int w  = threadIdx.x >> 6;
    for (int i = w; i < 64; i += 4)
        tile[lm][i] = __logf(conc[(size_t)(bt + i) * Mm + mt + lm]);
    __syncthreads();
    for (int i = w; i < 64; i += 4)
        logcT[(size_t)(mt + i) * Bsz + bt + lm] = tile[i][lm];
}

// ---- pass 2: scan E,S; buffer hits in LDS (lgkm path — no vmcnt drains),
// then one drain phase. Block m owns S-row m (no global atomics for S). ----
__global__ __launch_bounds__(256) void build_lists(
    const int* __restrict__ E, const int* __restrict__ S,
    int* __restrict__ ecnt, ushort_t* __restrict__ elist,
    int* __restrict__ scnt, ushort_t* __restrict__ slist)
{
    __shared__ int e_n, s_n;
    __shared__ int ebuf[256], sbuf[256];
    const int m = blockIdx.x;
    const int t = threadIdx.x;
    if (t == 0) { e_n = 0; s_n = 0; }
    __syncthreads();
    const int4* E4 = (const int4*)E + (size_t)m * 2048;
    const int4* S4 = (const int4*)S + (size_t)m * 2048;
    int4 e[8], s[8];
    #pragma unroll
    for (int u = 0; u < 8; ++u) e[u] = E4[t + 256 * u];
    #pragma unroll
    for (int u = 0; u < 8; ++u) s[u] = S4[t + 256 * u];
    #pragma unroll
    for (int u = 0; u < 8; ++u) {
        const int r0 = (t + 256 * u) << 2;
        int ev[4] = {e[u].x, e[u].y, e[u].z, e[u].w};
        int sv[4] = {s[u].x, s[u].y, s[u].z, s[u].w};
        #pragma unroll
        for (int q = 0; q < 4; ++q) {
            if (ev[q]) {
                int i = atomicAdd(&e_n, 1);                    // LDS atomic
                if (i < 256) ebuf[i] = (ev[q] << 13) | (r0 + q);
            }
            if (sv[q]) {
                int i = atomicAdd(&s_n, 1);                    // LDS atomic
                if (i < 256) sbuf[i] = ((sv[q] + 2) << 13) | (r0 + q);
            }
        }
    }
    __syncthreads();
    const int sn  = min(s_n, SMAX);
    if (t == 0) scnt[m] = sn;
    const int snp = (sn + 7) & ~7;                             // pad to int4 group
    if (t < snp)
        slist[m * SMAX + t] = (t < sn) ? (ushort_t)sbuf[t]
                                       : (ushort_t)0x4000;     // enc 2 -> s=0
    const int en = min(e_n, 256);
    if (t < en) {
        int wv = ebuf[t];
        int r  = wv & 0x1FFF;
        int evv = wv >> 13;
        int slot = atomicAdd(&ecnt[r], 1);                     // ~16/block, one drain
        if (slot < EMAX) elist[r * EMAX + slot] = (ushort_t)((evv << 11) | m);
    }
}

// ---- pass 3: VT[btile][r][4b] (fp16) = k*exp(gather from LDS logc slice) ----
// grid 256 = 128 b-tiles x 2 r-chunks; block 512
__global__ __launch_bounds__(512) void rates_kernel(
    const float* __restrict__ logcT, const float* __restrict__ kvec,
    const int* __restrict__ ecnt, const ushort_t* __restrict__ elist,
    __half* __restrict__ VTt)
{
    __shared__ float lc[Mm][9];                                // +1 pad: bank spread
    const int btile = blockIdx.x & 127;
    const int rc    = blockIdx.x >> 7;
    const int b0    = btile * 8;
    const int t     = threadIdx.x;
    const float2* src = (const float2*)logcT;                  // row pitch 512
    for (int i = t; i < Mm * 4; i += 512) {
        const int mm = i >> 2, j = i & 3;
        float2 v = src[mm * 512 + (b0 >> 1) + j];
        lc[mm][2 * j]     = v.x;
        lc[mm][2 * j + 1] = v.y;
    }
    __syncthreads();
    const int b  = t & 7;
    const int rg = t >> 3;                                     // 64 groups
    const int rend = rc * 4096 + 4096;
    for (int r = rc * 4096 + rg; r < rend; r += 64) {
        const int cnt = min(ecnt[r], EMAX);
        const ushort_t* row = elist + (r << 5);
        float acc = 0.f;
        for (int j = 0; j < cnt; j += 8) {                     // zero-padded groups
            int4 W = *(const int4*)(row + j);
            unsigned w;
            w = (unsigned)W.x;
            acc += (float)((w & 0xFFFF) >> 11) * lc[w & 0x7FF][b]
                 + (float)(w >> 27)            * lc[(w >> 16) & 0x7FF][b];
            w = (unsigned)W.y;
            acc += (float)((w & 0xFFFF) >> 11) * lc[w & 0x7FF][b]
                 + (float)(w >> 27)            * lc[(w >> 16) & 0x7FF][b];
            w = (unsigned)W.z;
            acc += (float)((w & 0xFFFF) >> 11) * lc[w & 0x7FF][b]
                 + (float)(w >> 27)            * lc[(w >> 16) & 0x7FF][b];
            w = (unsigned)W.w;
            acc += (float)((w & 0xFFFF) >> 11) * lc[w & 0x7FF][b]
                 + (float)(w >> 27)            * lc[(w >> 16) & 0x7FF][b];
        }
        const float vv = kvec[r] * __expf(acc);
        VTt[(size_t)((b0 + b) >> 2) * (Rr * 4) + r * 4 + ((b0 + b) & 3)] =
            __float2half(vv);
    }
}

// ---- pass 4: out[b][m] = sum s*VT; VT slice staged in LDS (coalesced) ----
// grid 256 b-tiles (ABT=4); block 512
__global__ __launch_bounds__(512) void assemble_kernel(
    const __half* __restrict__ VTt, const int* __restrict__ scnt,
    const ushort_t* __restrict__ slist, float* __restrict__ out)
{
    __shared__ __half vt[Rr * 4];                              // 64 KB
    const int btile = blockIdx.x;
    const int b0 = btile * 4;
    const int t  = threadIdx.x;
    const int4* src = (const int4*)(VTt + (size_t)btile * Rr * 4);
    int4* dst = (int4*)vt;
    for (int i = t; i < 4096; i += 512) dst[i] = src[i];       // 64 KB coalesced
    __syncthreads();
    const int b  = t & 3;
    const int mg = t >> 2;                                     // 128 groups
    for (int m = mg; m < Mm; m += 128) {
        const int cnt = min(scnt[m], SMAX);
        const ushort_t* row = slist + (m << 6);
        float acc = 0.f;
        for (int j = 0; j < cnt; j += 8) {                     // pad 0x4000 -> s=0
            int4 W = *(const int4*)(row + j);
            unsigned w;
            w = (unsigned)W.x;
            acc += (float)((int)((w & 0xFFFF) >> 13) - 2) * __half2float(vt[(w & 0x1FFF) * 4 + b]);
            acc += (float)((int)(w >> 29) - 2)            * __half2float(vt[((w >> 16) & 0x1FFF) * 4 + b]);
            w = (unsigned)W.y;
            acc += (float)((int)((w & 0xFFFF) >> 13) - 2) * __half2float(vt[(w & 0x1FFF) * 4 + b]);
            acc += (float)((int)(w >> 29) - 2)            * __half2float(vt[((w >> 16) & 0x1FFF) * 4 + b]);
            w = (unsigned)W.z;
            acc += (float)((int)((w & 0xFFFF) >> 13) - 2) * __half2float(vt[(w & 0x1FFF) * 4 + b]);
            acc += (float)((int)(w >> 29) - 2)            * __half2float(vt[((w >> 16) & 0x1FFF) * 4 + b]);
            w = (unsigned)W.w;
            acc += (float)((int)((w & 0xFFFF) >> 13) - 2) * __half2float(vt[(w & 0x1FFF) * 4 + b]);
            acc += (float)((int)(w >> 29) - 2)            * __half2float(vt[((w >> 16) & 0x1FFF) * 4 + b]);
        }
        out[(size_t)(b0 + b) * Mm + m] = acc;
    }
}

extern "C" void kernel_launch(void* const* d_in, const int* in_sizes, int n_in,
                              void* d_out, int out_size, void* d_ws, size_t ws_size,
                              hipStream_t stream) {
    const float* conc = (const float*)d_in[0];
    const int*   E    = (const int*)d_in[1];
    const int*   S    = (const int*)d_in[2];
    const float* kvec = (const float*)d_in[3];
    float* out = (float*)d_out;

    // ws: VTt fp16 (16 MB) | logcT fp32 (8 MB) | ecnt | scnt | elist u16 | slist u16
    __half* VTt      = (__half*)d_ws;
    float*  logcT    = (float*)((char*)d_ws + (size_t)Rr * Bsz * sizeof(__half));
    int*    ecnt     = (int*)(logcT + (size_t)Mm * Bsz);
    int*    scnt     = ecnt + Rr;
    ushort_t* elist  = (ushort_t*)(scnt + Mm);
    ushort_t* slist  = elist + Rr * EMAX;
    const size_t need = (size_t)Rr * Bsz * sizeof(__half)
                      + (size_t)Mm * Bsz * sizeof(float)
                      + (size_t)(Rr + Mm) * sizeof(int)
                      + (size_t)(Rr * EMAX + Mm * SMAX) * sizeof(ushort_t);
    if (ws_size < need) return;

    transpose_log<<<512, 256, 0, stream>>>(conc, logcT, ecnt, (unsigned int*)elist);
    build_lists<<<Mm, 256, 0, stream>>>(E, S, ecnt, elist, scnt, slist);
    rates_kernel<<<256, 512, 0, stream>>>(logcT, kvec, ecnt, elist, VTt);
    assemble_kernel<<<256, 512, 0, stream>>>(VTt, scnt, slist, out);
}

// Round 7
// 194.569 us; speedup vs baseline: 1.3657x; 1.3657x over previous
//
#include <hip/hip_runtime.h>
#include <hip/hip_fp16.h>

#define Bsz 1024
#define Mm  2048
#define Rr  8192
#define EMAX 32   // ushort slots per E column (col nnz mean ~4.1)
#define SMAX 64   // ushort slots per S row    (row nnz mean ~16.4)

typedef unsigned short ushort_t;

// ---- pass 1: logcTh[m][b] = (fp16) log(conc[b][m]); zero ecnt + ALL of elist ----
// grid MUST be 512 x 256 = 131072 threads == Rr*EMAX ushorts / 2 (uint32 zeroing)
__global__ __launch_bounds__(256) void transpose_log(
    const float* __restrict__ conc, __half2* __restrict__ logcTh2,
    int* __restrict__ ecnt, unsigned int* __restrict__ elist32)
{
    const int g = blockIdx.x * 256 + threadIdx.x;
    if (g < Rr) ecnt[g] = 0;
    elist32[g] = 0;                        // e=0, m=0 -> harmless pad entries

    __shared__ float tile[64][65];         // [m-off][b-off]
    const int mt = (blockIdx.x % (Mm / 64)) * 64;
    const int bt = (blockIdx.x / (Mm / 64)) * 64;
    const int lm = threadIdx.x & 63;
    const int w  = threadIdx.x >> 6;
    for (int i = w; i < 64; i += 4)
        tile[lm][i] = __logf(conc[(size_t)(bt + i) * Mm + mt + lm]);
    __syncthreads();
    // write half2 pairs: row m = mt+j, col pair bp
    for (int idx = threadIdx.x; idx < 64 * 32; idx += 256) {
        const int j  = idx >> 5;
        const int bp = idx & 31;
        logcTh2[((size_t)(mt + j) << 9) + (bt >> 1) + bp] =
            __floats2half2_rn(tile[j][2 * bp], tile[j][2 * bp + 1]);
    }
}

// ---- pass 2: grid 4096. Blocks 0..2047 scan E row m; 2048..4095 scan S row m.
// Each block streams ONE contiguous 32-KB row (stream-purity experiment). ----
__global__ __launch_bounds__(256) void build_lists(
    const int* __restrict__ E, const int* __restrict__ S,
    int* __restrict__ ecnt, ushort_t* __restrict__ elist,
    int* __restrict__ scnt, ushort_t* __restrict__ slist)
{
    __shared__ int n_hits;
    __shared__ int buf[256];
    const int t = threadIdx.x;
    if (t == 0) n_hits = 0;
    __syncthreads();

    if (blockIdx.x < 2048) {               // ---- E scanner ----
        const int m = blockIdx.x;
        const int4* E4 = (const int4*)E + (size_t)m * 2048;
        int4 e[8];
        #pragma unroll
        for (int u = 0; u < 8; ++u) e[u] = E4[t + 256 * u];
        #pragma unroll
        for (int u = 0; u < 8; ++u) {
            const int r0 = (t + 256 * u) << 2;
            int ev[4] = {e[u].x, e[u].y, e[u].z, e[u].w};
            #pragma unroll
            for (int q = 0; q < 4; ++q)
                if (ev[q]) {
                    int i = atomicAdd(&n_hits, 1);        // LDS atomic
                    if (i < 256) buf[i] = (ev[q] << 13) | (r0 + q);
                }
        }
        __syncthreads();
        const int en = min(n_hits, 256);
        if (t < en) {
            int wv = buf[t];
            int r  = wv & 0x1FFF;
            int ev = wv >> 13;
            int slot = atomicAdd(&ecnt[r], 1);            // ~16 atomics/block
            if (slot < EMAX) elist[r * EMAX + slot] = (ushort_t)((ev << 11) | m);
        }
    } else {                               // ---- S scanner (owns row m) ----
        const int m = blockIdx.x - 2048;
        const int4* S4 = (const int4*)S + (size_t)m * 2048;
        int4 s[8];
        #pragma unroll
        for (int u = 0; u < 8; ++u) s[u] = S4[t + 256 * u];
        #pragma unroll
        for (int u = 0; u < 8; ++u) {
            const int r0 = (t + 256 * u) << 2;
            int sv[4] = {s[u].x, s[u].y, s[u].z, s[u].w};
            #pragma unroll
            for (int q = 0; q < 4; ++q)
                if (sv[q]) {
                    int i = atomicAdd(&n_hits, 1);        // LDS atomic
                    if (i < 256) buf[i] = ((sv[q] + 2) << 13) | (r0 + q);
                }
        }
        __syncthreads();
        const int sn = min(n_hits, SMAX);
        if (t == 0) scnt[m] = sn;
        if (t < SMAX)                                     // fill ALL slots: pads safe
            slist[m * SMAX + t] = (t < sn) ? (ushort_t)buf[t]
                                           : (ushort_t)0x4000;   // enc 2 -> s=0
    }
}

// ---- pass 3: VTh[r][b2] (half2) = k[r]*exp(sum e*logcTh[m][b2]) ----
// lanes = half2 b-columns (coalesced); list rows wave-uniform; fixed-8 + tail
__global__ __launch_bounds__(256) void rates_kernel(
    const __half2* __restrict__ logcTh2, const float* __restrict__ kvec,
    const int* __restrict__ ecnt, const ushort_t* __restrict__ elist,
    __half2* __restrict__ VTh)
{
    const int rblk = blockIdx.x & 1023;          // Rr/8 = 1024
    const int bg   = blockIdx.x >> 10;           // 0..1 (slow-varying)
    const int b2   = bg * 256 + threadIdx.x;     // half2 column
    for (int rr = 0; rr < 8; ++rr) {
        const int r = rblk * 8 + rr;
        const ushort_t* row = elist + (r << 5);
        int4 W = *(const int4*)(row);            // 8 entries (zero-padded)
        float2 s = make_float2(0.f, 0.f);
        unsigned w; float2 g;
        #define EGATHER(word)                                                  \
            w = (unsigned)(word);                                              \
            g = __half22float2(logcTh2[(size_t)((w & 0x7FF) << 9) + b2]);      \
            s.x += (float)((w & 0xFFFF) >> 11) * g.x;                          \
            s.y += (float)((w & 0xFFFF) >> 11) * g.y;                          \
            g = __half22float2(logcTh2[(size_t)(((w >> 16) & 0x7FF) << 9) + b2]); \
            s.x += (float)(w >> 27) * g.x;                                     \
            s.y += (float)(w >> 27) * g.y;
        EGATHER(W.x) EGATHER(W.y) EGATHER(W.z) EGATHER(W.w)
        const int cnt = min(ecnt[r], EMAX);      // wave-uniform tail (rare)
        for (int j = 8; j < cnt; j += 8) {
            int4 T = *(const int4*)(row + j);
            EGATHER(T.x) EGATHER(T.y) EGATHER(T.z) EGATHER(T.w)
        }
        #undef EGATHER
        const float kk = kvec[r];
        VTh[((size_t)r << 9) + b2] =
            __floats2half2_rn(kk * __expf(s.x), kk * __expf(s.y));
    }
}

// ---- pass 4: out[b][m] = sum s*VTh[r][b2]; fixed-16 + grouped tail ----
__global__ __launch_bounds__(256) void assemble_kernel(
    const __half2* __restrict__ VTh,
    const int* __restrict__ scnt, const ushort_t* __restrict__ slist,
    float* __restrict__ out)
{
    const int mblk = blockIdx.x & 511;           // Mm/4 = 512
    const int bg   = blockIdx.x >> 9;            // 0..1 (slow-varying)
    const int b2   = bg * 256 + threadIdx.x;
    const int m0   = mblk * 4;
    float2 acc[4];
    #pragma unroll
    for (int mm = 0; mm < 4; ++mm) {
        const int m = m0 + mm;
        const ushort_t* row = slist + (m << 6);
        float2 a = make_float2(0.f, 0.f);
        unsigned w; float2 v; float sw;
        #define SGATHER(word)                                                  \
            w = (unsigned)(word);                                              \
            v = __half22float2(VTh[(size_t)((w & 0x1FFF) << 9) + b2]);         \
            sw = (float)((int)((w & 0xFFFF) >> 13) - 2);                       \
            a.x += sw * v.x;  a.y += sw * v.y;                                 \
            v = __half22float2(VTh[(size_t)(((w >> 16) & 0x1FFF) << 9) + b2]); \
            sw = (float)((int)(w >> 29) - 2);                                  \
            a.x += sw * v.x;  a.y += sw * v.y;
        int4 W0 = *(const int4*)(row);
        int4 W1 = *(const int4*)(row + 8);       // rows always fully padded
        SGATHER(W0.x) SGATHER(W0.y) SGATHER(W0.z) SGATHER(W0.w)
        SGATHER(W1.x) SGATHER(W1.y) SGATHER(W1.z) SGATHER(W1.w)
        const int cnt = min(scnt[m], SMAX);      // wave-uniform tail
        for (int j = 16; j < cnt; j += 8) {
            int4 T = *(const int4*)(row + j);
            SGATHER(T.x) SGATHER(T.y) SGATHER(T.z) SGATHER(T.w)
        }
        #undef SGATHER
        acc[mm] = a;
    }
    const int b = 2 * b2;
    *(float4*)(out + (size_t)b * Mm + m0) =
        make_float4(acc[0].x, acc[1].x, acc[2].x, acc[3].x);
    *(float4*)(out + (size_t)(b + 1) * Mm + m0) =
        make_float4(acc[0].y, acc[1].y, acc[2].y, acc[3].y);
}

extern "C" void kernel_launch(void* const* d_in, const int* in_sizes, int n_in,
                              void* d_out, int out_size, void* d_ws, size_t ws_size,
                              hipStream_t stream) {
    const float* conc = (const float*)d_in[0];
    const int*   E    = (const int*)d_in[1];
    const int*   S    = (const int*)d_in[2];
    const float* kvec = (const float*)d_in[3];
    float* out = (float*)d_out;

    // ws: VTh fp16 (16 MB) | logcTh fp16 (4 MB) | ecnt | scnt | elist u16 | slist u16
    __half2* VTh     = (__half2*)d_ws;
    __half2* logcTh2 = (__half2*)((char*)d_ws + (size_t)Rr * Bsz * sizeof(__half));
    int*    ecnt     = (int*)((char*)logcTh2 + (size_t)Mm * Bsz * sizeof(__half));
    int*    scnt     = ecnt + Rr;
    ushort_t* elist  = (ushort_t*)(scnt + Mm);
    ushort_t* slist  = elist + Rr * EMAX;
    const size_t need = (size_t)Rr * Bsz * sizeof(__half)
                      + (size_t)Mm * Bsz * sizeof(__half)
                      + (size_t)(Rr + Mm) * sizeof(int)
                      + (size_t)(Rr * EMAX + Mm * SMAX) * sizeof(ushort_t);
    if (ws_size < need) return;

    transpose_log<<<512, 256, 0, stream>>>(conc, logcTh2, ecnt, (unsigned int*)elist);
    build_lists<<<4096, 256, 0, stream>>>(E, S, ecnt, elist, scnt, slist);
    rates_kernel<<<2048, 256, 0, stream>>>(logcTh2, kvec, ecnt, elist, VTh);
    assemble_kernel<<<1024, 256, 0, stream>>>(VTh, scnt, slist, out);
}

// Round 8
// 193.841 us; speedup vs baseline: 1.3708x; 1.0038x over previous
//
#include <hip/hip_runtime.h>
#include <hip/hip_fp16.h>

#define Bsz 1024
#define Mm  2048
#define Rr  8192
#define EMAX 32   // ushort slots per E column (col nnz mean ~4.1)
#define SMAX 64   // ushort slots per S row    (row nnz mean ~16.4)

typedef unsigned short ushort_t;

// ---- pass 1: logcTh[m][b] = (fp16) log(conc[b][m]); zero ecnt + ALL of elist ----
// grid MUST be 512 x 256 = 131072 threads == Rr*EMAX ushorts / 2 (uint32 zeroing)
__global__ __launch_bounds__(256) void transpose_log(
    const float* __restrict__ conc, __half2* __restrict__ logcTh2,
    int* __restrict__ ecnt, unsigned int* __restrict__ elist32)
{
    const int g = blockIdx.x * 256 + threadIdx.x;
    if (g < Rr) ecnt[g] = 0;
    elist32[g] = 0;                        // e=0, m=0 -> harmless pad entries

    __shared__ float tile[64][65];         // [m-off][b-off]
    const int mt = (blockIdx.x % (Mm / 64)) * 64;
    const int bt = (blockIdx.x / (Mm / 64)) * 64;
    const int lm = threadIdx.x & 63;
    const int w  = threadIdx.x >> 6;
    for (int i = w; i < 64; i += 4)
        tile[lm][i] = __logf(conc[(size_t)(bt + i) * Mm + mt + lm]);
    __syncthreads();
    // write half2 pairs: row m = mt+j, col pair bp
    for (int idx = threadIdx.x; idx < 64 * 32; idx += 256) {
        const int j  = idx >> 5;
        const int bp = idx & 31;
        logcTh2[((size_t)(mt + j) << 9) + (bt >> 1) + bp] =
            __floats2half2_rn(tile[j][2 * bp], tile[j][2 * bp + 1]);
    }
}

// ---- pass 2: grid 4096. Blocks 0..2047 scan E row m; 2048..4095 scan S row m. ----
// At structural ingest ceiling (~52 us for 128 MB) — do not touch.
__global__ __launch_bounds__(256) void build_lists(
    const int* __restrict__ E, const int* __restrict__ S,
    int* __restrict__ ecnt, ushort_t* __restrict__ elist,
    int* __restrict__ scnt, ushort_t* __restrict__ slist)
{
    __shared__ int n_hits;
    __shared__ int buf[256];
    const int t = threadIdx.x;
    if (t == 0) n_hits = 0;
    __syncthreads();

    if (blockIdx.x < 2048) {               // ---- E scanner ----
        const int m = blockIdx.x;
        const int4* E4 = (const int4*)E + (size_t)m * 2048;
        int4 e[8];
        #pragma unroll
        for (int u = 0; u < 8; ++u) e[u] = E4[t + 256 * u];
        #pragma unroll
        for (int u = 0; u < 8; ++u) {
            const int r0 = (t + 256 * u) << 2;
            int ev[4] = {e[u].x, e[u].y, e[u].z, e[u].w};
            #pragma unroll
            for (int q = 0; q < 4; ++q)
                if (ev[q]) {
                    int i = atomicAdd(&n_hits, 1);        // LDS atomic
                    if (i < 256) buf[i] = (ev[q] << 13) | (r0 + q);
                }
        }
        __syncthreads();
        const int en = min(n_hits, 256);
        if (t < en) {
            int wv = buf[t];
            int r  = wv & 0x1FFF;
            int ev = wv >> 13;
            int slot = atomicAdd(&ecnt[r], 1);            // ~16 atomics/block
            if (slot < EMAX) elist[r * EMAX + slot] = (ushort_t)((ev << 11) | m);
        }
    } else {                               // ---- S scanner (owns row m) ----
        const int m = blockIdx.x - 2048;
        const int4* S4 = (const int4*)S + (size_t)m * 2048;
        int4 s[8];
        #pragma unroll
        for (int u = 0; u < 8; ++u) s[u] = S4[t + 256 * u];
        #pragma unroll
        for (int u = 0; u < 8; ++u) {
            const int r0 = (t + 256 * u) << 2;
            int sv[4] = {s[u].x, s[u].y, s[u].z, s[u].w};
            #pragma unroll
            for (int q = 0; q < 4; ++q)
                if (sv[q]) {
                    int i = atomicAdd(&n_hits, 1);        // LDS atomic
                    if (i < 256) buf[i] = ((sv[q] + 2) << 13) | (r0 + q);
                }
        }
        __syncthreads();
        const int sn = min(n_hits, SMAX);
        if (t == 0) scnt[m] = sn;
        if (t < SMAX)                                     // fill ALL slots: pads safe
            slist[m * SMAX + t] = (t < sn) ? (ushort_t)buf[t]
                                           : (ushort_t)0x4000;   // enc 2 -> s=0
    }
}

// ---- pass 3: VTh[r][b2] (half2) = k[r]*exp(sum e*logcTh[m][b2]) ----
// fixed-4 first group (int2) + wave-uniform 4-entry tail groups (zero-padded)
__global__ __launch_bounds__(256) void rates_kernel(
    const __half2* __restrict__ logcTh2, const float* __restrict__ kvec,
    const int* __restrict__ ecnt, const ushort_t* __restrict__ elist,
    __half2* __restrict__ VTh)
{
    const int rblk = blockIdx.x & 1023;          // Rr/8 = 1024
    const int bg   = blockIdx.x >> 10;           // 0..1 (slow-varying)
    const int b2   = bg * 256 + threadIdx.x;     // half2 column
    for (int rr = 0; rr < 8; ++rr) {
        const int r = rblk * 8 + rr;
        const ushort_t* row = elist + (r << 5);
        float2 s = make_float2(0.f, 0.f);
        unsigned w; float2 g;
        #define EGATHER(word)                                                  \
            w = (unsigned)(word);                                              \
            g = __half22float2(logcTh2[(size_t)((w & 0x7FF) << 9) + b2]);      \
            s.x += (float)((w & 0xFFFF) >> 11) * g.x;                          \
            s.y += (float)((w & 0xFFFF) >> 11) * g.y;                          \
            g = __half22float2(logcTh2[(size_t)(((w >> 16) & 0x7FF) << 9) + b2]); \
            s.x += (float)(w >> 27) * g.x;                                     \
            s.y += (float)(w >> 27) * g.y;
        int2 W = *(const int2*)(row);            // 4 entries (zero-padded)
        EGATHER(W.x) EGATHER(W.y)
        const int cnt = min(ecnt[r], EMAX);      // wave-uniform tail (37% of rows)
        for (int j = 4; j < cnt; j += 4) {
            int2 T = *(const int2*)(row + j);
            EGATHER(T.x) EGATHER(T.y)
        }
        #undef EGATHER
        const float kk = kvec[r];
        VTh[((size_t)r << 9) + b2] =
            __floats2half2_rn(kk * __expf(s.x), kk * __expf(s.y));
    }
}

// ---- pass 4: out[b][m] = sum s*VTh[r][b2]; fixed-16 + grouped tail ----
__global__ __launch_bounds__(256) void assemble_kernel(
    const __half2* __restrict__ VTh,
    const int* __restrict__ scnt, const ushort_t* __restrict__ slist,
    float* __restrict__ out)
{
    const int mblk = blockIdx.x & 511;           // Mm/4 = 512
    const int bg   = blockIdx.x >> 9;            // 0..1 (slow-varying)
    const int b2   = bg * 256 + threadIdx.x;
    const int m0   = mblk * 4;
    float2 acc[4];
    #pragma unroll
    for (int mm = 0; mm < 4; ++mm) {
        const int m = m0 + mm;
        const ushort_t* row = slist + (m << 6);
        float2 a = make_float2(0.f, 0.f);
        unsigned w; float2 v; float sw;
        #define SGATHER(word)                                                  \
            w = (unsigned)(word);                                              \
            v = __half22float2(VTh[(size_t)((w & 0x1FFF) << 9) + b2]);         \
            sw = (float)((int)((w & 0xFFFF) >> 13) - 2);                       \
            a.x += sw * v.x;  a.y += sw * v.y;                                 \
            v = __half22float2(VTh[(size_t)(((w >> 16) & 0x1FFF) << 9) + b2]); \
            sw = (float)((int)(w >> 29) - 2);                                  \
            a.x += sw * v.x;  a.y += sw * v.y;
        int4 W0 = *(const int4*)(row);
        int4 W1 = *(const int4*)(row + 8);       // rows always fully padded
        SGATHER(W0.x) SGATHER(W0.y) SGATHER(W0.z) SGATHER(W0.w)
        SGATHER(W1.x) SGATHER(W1.y) SGATHER(W1.z) SGATHER(W1.w)
        const int cnt = min(scnt[m], SMAX);      // wave-uniform tail
        for (int j = 16; j < cnt; j += 8) {
            int4 T = *(const int4*)(row + j);
            SGATHER(T.x) SGATHER(T.y) SGATHER(T.z) SGATHER(T.w)
        }
        #undef SGATHER
        acc[mm] = a;
    }
    const int b = 2 * b2;
    *(float4*)(out + (size_t)b * Mm + m0) =
        make_float4(acc[0].x, acc[1].x, acc[2].x, acc[3].x);
    *(float4*)(out + (size_t)(b + 1) * Mm + m0) =
        make_float4(acc[0].y, acc[1].y, acc[2].y, acc[3].y);
}

extern "C" void kernel_launch(void* const* d_in, const int* in_sizes, int n_in,
                              void* d_out, int out_size, void* d_ws, size_t ws_size,
                              hipStream_t stream) {
    const float* conc = (const float*)d_in[0];
    const int*   E    = (const int*)d_in[1];
    const int*   S    = (const int*)d_in[2];
    const float* kvec = (const float*)d_in[3];
    float* out = (float*)d_out;

    // ws: VTh fp16 (16 MB) | logcTh fp16 (4 MB) | ecnt | scnt | elist u16 | slist u16
    __half2* VTh     = (__half2*)d_ws;
    __half2* logcTh2 = (__half2*)((char*)d_ws + (size_t)Rr * Bsz * sizeof(__half));
    int*    ecnt     = (int*)((char*)logcTh2 + (size_t)Mm * Bsz * sizeof(__half));
    int*    scnt     = ecnt + Rr;
    ushort_t* elist  = (ushort_t*)(scnt + Mm);
    ushort_t* slist  = elist + Rr * EMAX;
    const size_t need = (size_t)Rr * Bsz * sizeof(__half)
                      + (size_t)Mm * Bsz * sizeof(__half)
                      + (size_t)(Rr + Mm) * sizeof(int)
                      + (size_t)(Rr * EMAX + Mm * SMAX) * sizeof(ushort_t);
    if (ws_size < need) return;

    transpose_log<<<512, 256, 0, stream>>>(conc, logcTh2, ecnt, (unsigned int*)elist);
    build_lists<<<4096, 256, 0, stream>>>(E, S, ecnt, elist, scnt, slist);
    rates_kernel<<<2048, 256, 0, stream>>>(logcTh2, kvec, ecnt, elist, VTh);
    assemble_kernel<<<1024, 256, 0, stream>>>(VTh, scnt, slist, out);
}

// Round 9
// 193.097 us; speedup vs baseline: 1.3761x; 1.0039x over previous
//
#include <hip/hip_runtime.h>
#include <hip/hip_fp16.h>

#define Bsz 1024
#define Mm  2048
#define Rr  8192
#define EMAX 32   // ushort slots per E column (col nnz mean ~4.1)
#define SMAX 64   // ushort slots per S row    (row nnz mean ~16.4)

typedef unsigned short ushort_t;

// ---- pass 1: logcTh[s][m][64] (fp16, b-slice-major); zero ecnt + ALL of elist ----
// grid MUST be 512 x 256 = 131072 threads == Rr*EMAX ushorts / 2 (uint32 zeroing)
__global__ __launch_bounds__(256) void transpose_log(
    const float* __restrict__ conc, __half2* __restrict__ logcTh2,
    int* __restrict__ ecnt, unsigned int* __restrict__ elist32)
{
    const int g = blockIdx.x * 256 + threadIdx.x;
    if (g < Rr) ecnt[g] = 0;
    elist32[g] = 0;                        // e=0, m=0 -> harmless pad entries

    __shared__ float tile[64][65];         // [m-off][b-off]
    const int mt = (blockIdx.x % (Mm / 64)) * 64;
    const int bt = (blockIdx.x / (Mm / 64)) * 64;
    const int lm = threadIdx.x & 63;
    const int w  = threadIdx.x >> 6;
    for (int i = w; i < 64; i += 4)
        tile[lm][i] = __logf(conc[(size_t)(bt + i) * Mm + mt + lm]);
    __syncthreads();
    const int s       = bt >> 7;           // b-slice (128 b each)
    const int colbase = (bt & 127) >> 1;   // 0 or 32 (half2 cols within slice)
    __half2* dst = logcTh2 + (size_t)s * (Mm * 64);
    for (int idx = threadIdx.x; idx < 64 * 32; idx += 256) {
        const int j  = idx >> 5;           // m offset
        const int bp = idx & 31;           // half2 col within this 64-b tile
        dst[(mt + j) * 64 + colbase + bp] =
            __floats2half2_rn(tile[j][2 * bp], tile[j][2 * bp + 1]);
    }
}

// ---- pass 2: grid 4096. Blocks 0..2047 scan E row m; 2048..4095 scan S row m. ----
// At structural ingest ceiling (~50 us for 128 MB dense scan) — do not touch.
__global__ __launch_bounds__(256) void build_lists(
    const int* __restrict__ E, const int* __restrict__ S,
    int* __restrict__ ecnt, ushort_t* __restrict__ elist,
    int* __restrict__ scnt, ushort_t* __restrict__ slist)
{
    __shared__ int n_hits;
    __shared__ int buf[256];
    const int t = threadIdx.x;
    if (t == 0) n_hits = 0;
    __syncthreads();

    if (blockIdx.x < 2048) {               // ---- E scanner ----
        const int m = blockIdx.x;
        const int4* E4 = (const int4*)E + (size_t)m * 2048;
        int4 e[8];
        #pragma unroll
        for (int u = 0; u < 8; ++u) e[u] = E4[t + 256 * u];
        #pragma unroll
        for (int u = 0; u < 8; ++u) {
            const int r0 = (t + 256 * u) << 2;
            int ev[4] = {e[u].x, e[u].y, e[u].z, e[u].w};
            #pragma unroll
            for (int q = 0; q < 4; ++q)
                if (ev[q]) {
                    int i = atomicAdd(&n_hits, 1);        // LDS atomic
                    if (i < 256) buf[i] = (ev[q] << 13) | (r0 + q);
                }
        }
        __syncthreads();
        const int en = min(n_hits, 256);
        if (t < en) {
            int wv = buf[t];
            int r  = wv & 0x1FFF;
            int ev = wv >> 13;
            int slot = atomicAdd(&ecnt[r], 1);            // ~16 atomics/block
            if (slot < EMAX) elist[r * EMAX + slot] = (ushort_t)((ev << 11) | m);
        }
    } else {                               // ---- S scanner (owns row m) ----
        const int m = blockIdx.x - 2048;
        const int4* S4 = (const int4*)S + (size_t)m * 2048;
        int4 s[8];
        #pragma unroll
        for (int u = 0; u < 8; ++u) s[u] = S4[t + 256 * u];
        #pragma unroll
        for (int u = 0; u < 8; ++u) {
            const int r0 = (t + 256 * u) << 2;
            int sv[4] = {s[u].x, s[u].y, s[u].z, s[u].w};
            #pragma unroll
            for (int q = 0; q < 4; ++q)
                if (sv[q]) {
                    int i = atomicAdd(&n_hits, 1);        // LDS atomic
                    if (i < 256) buf[i] = ((sv[q] + 2) << 13) | (r0 + q);
                }
        }
        __syncthreads();
        const int sn = min(n_hits, SMAX);
        if (t == 0) scnt[m] = sn;
        if (t < SMAX)                                     // fill ALL slots: pads safe
            slist[m * SMAX + t] = (t < sn) ? (ushort_t)buf[t]
                                           : (ushort_t)0x4000;   // enc 2 -> s=0
    }
}

// ---- pass 3: VTh[s][r][64] = k[r]*exp(sum e*logcTh[s][m][64]) ----
// slice s = blockIdx&7 (XCD pin); one wave per r; lists wave-uniform
__global__ __launch_bounds__(256) void rates_kernel(
    const __half2* __restrict__ logcTh2, const float* __restrict__ kvec,
    const int* __restrict__ ecnt, const ushort_t* __restrict__ elist,
    __half2* __restrict__ VTh)
{
    const int s   = blockIdx.x & 7;
    const int rch = blockIdx.x >> 3;             // 0..255, 32 r each
    const int col = threadIdx.x & 63;            // half2 col within slice
    const int wr  = threadIdx.x >> 6;            // wave -> r sub-lane
    const __half2* lc = logcTh2 + (size_t)s * (Mm * 64);
    __half2* vt = VTh + (size_t)s * (Rr * 64);
    unsigned w; float2 g;
    #define EGATHER(word)                                                  \
        w = (unsigned)(word);                                              \
        g = __half22float2(lc[(w & 0x7FF) * 64 + col]);                    \
        acc.x += (float)((w & 0xFFFF) >> 11) * g.x;                        \
        acc.y += (float)((w & 0xFFFF) >> 11) * g.y;                        \
        g = __half22float2(lc[((w >> 16) & 0x7FF) * 64 + col]);            \
        acc.x += (float)(w >> 27) * g.x;                                   \
        acc.y += (float)(w >> 27) * g.y;
    for (int i = 0; i < 8; ++i) {
        const int r = rch * 32 + i * 4 + wr;
        const ushort_t* row = elist + (r << 5);
        float2 acc = make_float2(0.f, 0.f);
        int2 W = *(const int2*)(row);            // 4 entries (zero-padded)
        EGATHER(W.x) EGATHER(W.y)
        const int cnt = min(ecnt[r], EMAX);      // wave-uniform tail
        for (int j = 4; j < cnt; j += 4) {
            int2 T = *(const int2*)(row + j);
            EGATHER(T.x) EGATHER(T.y)
        }
        const float kk = kvec[r];
        vt[r * 64 + col] = __floats2half2_rn(kk * __expf(acc.x), kk * __expf(acc.y));
    }
    #undef EGATHER
}

// ---- pass 4: out[b][m] = sum s*VTh[s][r][64]; LDS transpose -> 64B stores ----
// slice s = blockIdx&7 (same XCD pin as rates: VTh slice stays in that L2)
__global__ __launch_bounds__(256) void assemble_kernel(
    const __half2* __restrict__ VTh, const int* __restrict__ scnt,
    const ushort_t* __restrict__ slist, float* __restrict__ out)
{
    __shared__ float tile[128][17];              // [b-local][m-local] 8.5 KB
    const int s   = blockIdx.x & 7;
    const int mch = blockIdx.x >> 3;             // 0..127, 16 m each
    const int col = threadIdx.x & 63;
    const int wm  = threadIdx.x >> 6;
    const __half2* vt = VTh + (size_t)s * (Rr * 64);
    const int m0 = mch * 16;
    unsigned w; float2 v; float sw;
    #define SGATHER(word)                                                  \
        w = (unsigned)(word);                                              \
        v = __half22float2(vt[(w & 0x1FFF) * 64 + col]);                   \
        sw = (float)((int)((w & 0xFFFF) >> 13) - 2);                       \
        a.x += sw * v.x;  a.y += sw * v.y;                                 \
        v = __half22float2(vt[((w >> 16) & 0x1FFF) * 64 + col]);           \
        sw = (float)((int)(w >> 29) - 2);                                  \
        a.x += sw * v.x;  a.y += sw * v.y;
    for (int i = 0; i < 4; ++i) {
        const int ml = i * 4 + wm;
        const int m  = m0 + ml;
        const ushort_t* row = slist + (m << 6);
        float2 a = make_float2(0.f, 0.f);
        int4 W0 = *(const int4*)(row);           // rows always fully padded
        int4 W1 = *(const int4*)(row + 8);
        SGATHER(W0.x) SGATHER(W0.y) SGATHER(W0.z) SGATHER(W0.w)
        SGATHER(W1.x) SGATHER(W1.y) SGATHER(W1.z) SGATHER(W1.w)
        const int cnt = min(scnt[m], SMAX);      // wave-uniform tail
        for (int j = 16; j < cnt; j += 8) {
            int4 T = *(const int4*)(row + j);
            SGATHER(T.x) SGATHER(T.y) SGATHER(T.z) SGATHER(T.w)
        }
        tile[2 * col][ml]     = a.x;
        tile[2 * col + 1][ml] = a.y;
    }
    #undef SGATHER
    __syncthreads();
    #pragma unroll
    for (int pass = 0; pass < 2; ++pass) {
        const int bl = (threadIdx.x >> 2) + pass * 64;
        const int fl = threadIdx.x & 3;
        float4 vv = *(const float4*)&tile[bl][fl * 4];
        *(float4*)(out + (size_t)(s * 128 + bl) * Mm + m0 + fl * 4) = vv;
    }
}

extern "C" void kernel_launch(void* const* d_in, const int* in_sizes, int n_in,
                              void* d_out, int out_size, void* d_ws, size_t ws_size,
                              hipStream_t stream) {
    const float* conc = (const float*)d_in[0];
    const int*   E    = (const int*)d_in[1];
    const int*   S    = (const int*)d_in[2];
    const float* kvec = (const float*)d_in[3];
    float* out = (float*)d_out;

    // ws: VTh fp16 (16 MB) | logcTh fp16 (4 MB) | ecnt | scnt | elist u16 | slist u16
    __half2* VTh     = (__half2*)d_ws;
    __half2* logcTh2 = (__half2*)((char*)d_ws + (size_t)Rr * Bsz * sizeof(__half));
    int*    ecnt     = (int*)((char*)logcTh2 + (size_t)Mm * Bsz * sizeof(__half));
    int*    scnt     = ecnt + Rr;
    ushort_t* elist  = (ushort_t*)(scnt + Mm);
    ushort_t* slist  = elist + Rr * EMAX;
    const size_t need = (size_t)Rr * Bsz * sizeof(__half)
                      + (size_t)Mm * Bsz * sizeof(__half)
                      + (size_t)(Rr + Mm) * sizeof(int)
                      + (size_t)(Rr * EMAX + Mm * SMAX) * sizeof(ushort_t);
    if (ws_size < need) return;

    transpose_log<<<512, 256, 0, stream>>>(conc, logcTh2, ecnt, (unsigned int*)elist);
    build_lists<<<4096, 256, 0, stream>>>(E, S, ecnt, elist, scnt, slist);
    rates_kernel<<<2048, 256, 0, stream>>>(logcTh2, kvec, ecnt, elist, VTh);
    assemble_kernel<<<1024, 256, 0, stream>>>(VTh, scnt, slist, out);
}